// Round 1
// baseline (660.021 us; speedup 1.0000x reference)
//
#include <hip/hip_runtime.h>
#include <math.h>

#define N_NODES_C  500000
#define N_EDGES_C  8000000
#define N_GRAPHS_C 1000

// workspace layout (float offsets)
#define NODE_ACC_OFF  0          // 500000 floats
#define GRAPH_ACC_OFF 500000     // 11000 floats (1000 graphs x 11 feats)
#define FW_OFF        512000     // 207 floats of fused weights
#define ZERO_LEN      511000     // node_acc + graph_acc

// fused-weight layout inside fw[]
// 0   : w_pn1[20]   (2x10 row-major)
// 20  : b_pn1[10]
// 30  : W_eb[50]    (10x5) = pn_w2 @ ue_w1[1:,:]
// 80  : b_eb[5]     = pn_b2 @ ue_w1[1:,:] + ue_b1
// 85  : w1r0_e[5]   = ue_w1[0,:]
// 90  : w2_e[5]     = ue_w2
// 95  : b2_e[1]     = ue_b2
// 96  : w_pe1[5]
// 101 : b_pe1[5]
// 106 : pe_w2[50]   (5x10)
// 156 : pe_b2[10]
// 166 : W_nb[25]    (5x5)  = pe_w2 @ un_w1[1:,:]
// 191 : b_nb[5]     = pe_b2 @ un_w1[1:,:] + un_b1
// 196 : w1r0_n[5]   = un_w1[0,:]
// 201 : w2_n[5]     = un_w2
// 206 : b2_n[1]     = un_b2

__device__ __forceinline__ float selu_f(float x) {
    const float scale = 1.0507009873554805f;
    const float sa    = 1.0507009873554805f * 1.6732632423543772f;
    float neg = sa * (__expf(x) - 1.0f);
    return x > 0.0f ? scale * x : neg;
}

__device__ __forceinline__ void atomAddF(float* p, float v) {
    __hip_atomic_fetch_add(p, v, __ATOMIC_RELAXED, __HIP_MEMORY_SCOPE_AGENT);
}

__global__ void k_zero(float* __restrict__ ws) {
    int i = blockIdx.x * blockDim.x + threadIdx.x;
    if (i < ZERO_LEN) ws[i] = 0.0f;
}

__global__ void k_fuse(const float* __restrict__ pn_w1, const float* __restrict__ pn_b1,
                       const float* __restrict__ pn_w2, const float* __restrict__ pn_b2,
                       const float* __restrict__ ue_w1, const float* __restrict__ ue_b1,
                       const float* __restrict__ ue_w2, const float* __restrict__ ue_b2,
                       const float* __restrict__ pe_w1, const float* __restrict__ pe_b1,
                       const float* __restrict__ pe_w2, const float* __restrict__ pe_b2,
                       const float* __restrict__ un_w1, const float* __restrict__ un_b1,
                       const float* __restrict__ un_w2, const float* __restrict__ un_b2,
                       float* __restrict__ fw) {
    int t = threadIdx.x;
    if (t < 20) fw[0 + t] = pn_w1[t];
    if (t < 10) fw[20 + t] = pn_b1[t];
    if (t < 50) {                       // W_eb (10x5)
        int j = t / 5, k = t % 5;
        float s = 0.0f;
        for (int m = 0; m < 10; ++m) s += pn_w2[j * 10 + m] * ue_w1[(1 + m) * 5 + k];
        fw[30 + t] = s;
    }
    if (t < 5) {                        // b_eb
        float s = ue_b1[t];
        for (int m = 0; m < 10; ++m) s += pn_b2[m] * ue_w1[(1 + m) * 5 + t];
        fw[80 + t] = s;
    }
    if (t < 5)  fw[85 + t]  = ue_w1[t];   // row 0 of ue_w1
    if (t < 5)  fw[90 + t]  = ue_w2[t];
    if (t == 0) fw[95]      = ue_b2[0];
    if (t < 5)  fw[96 + t]  = pe_w1[t];
    if (t < 5)  fw[101 + t] = pe_b1[t];
    if (t < 50) fw[106 + t] = pe_w2[t];
    if (t < 10) fw[156 + t] = pe_b2[t];
    if (t < 25) {                       // W_nb (5x5)
        int j = t / 5, k = t % 5;
        float s = 0.0f;
        for (int m = 0; m < 10; ++m) s += pe_w2[j * 10 + m] * un_w1[(1 + m) * 5 + k];
        fw[166 + t] = s;
    }
    if (t < 5) {                        // b_nb
        float s = un_b1[t];
        for (int m = 0; m < 10; ++m) s += pe_b2[m] * un_w1[(1 + m) * 5 + t];
        fw[191 + t] = s;
    }
    if (t < 5)  fw[196 + t] = un_w1[t];
    if (t < 5)  fw[201 + t] = un_w2[t];
    if (t == 0) fw[206]     = un_b2[0];
}

__global__ __launch_bounds__(256) void k_edges(
        const float* __restrict__ nodes, const float* __restrict__ edges,
        const int* __restrict__ senders, const int* __restrict__ receivers,
        const float* __restrict__ fw, float* __restrict__ node_acc) {
    // load fused weights (uniform addresses; compiler hoists/merges)
    float w_pn1[20], b_pn1[10], W_eb[50], b_eb[5], w1r0[5], w2e[5];
#pragma unroll
    for (int j = 0; j < 20; ++j) w_pn1[j] = fw[j];
#pragma unroll
    for (int j = 0; j < 10; ++j) b_pn1[j] = fw[20 + j];
#pragma unroll
    for (int j = 0; j < 50; ++j) W_eb[j] = fw[30 + j];
#pragma unroll
    for (int j = 0; j < 5; ++j) b_eb[j] = fw[80 + j];
#pragma unroll
    for (int j = 0; j < 5; ++j) w1r0[j] = fw[85 + j];
#pragma unroll
    for (int j = 0; j < 5; ++j) w2e[j] = fw[90 + j];
    float b2e = fw[95];

    int g = blockIdx.x * 256 + threadIdx.x;       // group of 4 edges
    if (g >= N_EDGES_C / 4) return;

    float4 e4 = ((const float4*)edges)[g];
    int4  s4 = ((const int4*)senders)[g];
    int4  r4 = ((const int4*)receivers)[g];
    float ev[4] = {e4.x, e4.y, e4.z, e4.w};
    int   sv[4] = {s4.x, s4.y, s4.z, s4.w};
    int   rv[4] = {r4.x, r4.y, r4.z, r4.w};

    float nsv[4], nrv[4];
#pragma unroll
    for (int u = 0; u < 4; ++u) { nsv[u] = nodes[sv[u]]; nrv[u] = nodes[rv[u]]; }

#pragma unroll
    for (int u = 0; u < 4; ++u) {
        float nr = nrv[u], ns = nsv[u];
        float base[5];
#pragma unroll
        for (int k = 0; k < 5; ++k) base[k] = b_eb[k];
#pragma unroll
        for (int j = 0; j < 10; ++j) {
            float z  = fmaf(nr, w_pn1[j], fmaf(ns, w_pn1[10 + j], b_pn1[j]));
            float sz = selu_f(z);
#pragma unroll
            for (int k = 0; k < 5; ++k) base[k] = fmaf(sz, W_eb[j * 5 + k], base[k]);
        }
        float e = ev[u];
#pragma unroll
        for (int it = 0; it < 3; ++it) {
            float acc = b2e;
#pragma unroll
            for (int k = 0; k < 5; ++k) {
                float tt = selu_f(fmaf(e, w1r0[k], base[k]));
                acc = fmaf(tt, w2e[k], acc);
            }
            e = acc;
        }
        atomAddF(&node_acc[rv[u]], e);
    }
}

__global__ __launch_bounds__(256) void k_nodes(
        const float* __restrict__ nodes, const int* __restrict__ graph_ids,
        const float* __restrict__ fw, const float* __restrict__ node_acc,
        float* __restrict__ graph_acc) {
    float w_pe1[5], b_pe1[5], pe_w2[50], pe_b2[10], W_nb[25], b_nb[5], w1r0n[5], w2n[5];
#pragma unroll
    for (int j = 0; j < 5; ++j) w_pe1[j] = fw[96 + j];
#pragma unroll
    for (int j = 0; j < 5; ++j) b_pe1[j] = fw[101 + j];
#pragma unroll
    for (int j = 0; j < 50; ++j) pe_w2[j] = fw[106 + j];
#pragma unroll
    for (int j = 0; j < 10; ++j) pe_b2[j] = fw[156 + j];
#pragma unroll
    for (int j = 0; j < 25; ++j) W_nb[j] = fw[166 + j];
#pragma unroll
    for (int j = 0; j < 5; ++j) b_nb[j] = fw[191 + j];
#pragma unroll
    for (int j = 0; j < 5; ++j) w1r0n[j] = fw[196 + j];
#pragma unroll
    for (int j = 0; j < 5; ++j) w2n[j] = fw[201 + j];
    float b2n = fw[206];

    int i = blockIdx.x * 256 + threadIdx.x;
    bool valid = i < N_NODES_C;
    int ii = valid ? i : (N_NODES_C - 1);

    float s = node_acc[ii];
    float t5[5];
#pragma unroll
    for (int k = 0; k < 5; ++k) t5[k] = selu_f(fmaf(s, w_pe1[k], b_pe1[k]));
    float he[10];
#pragma unroll
    for (int m = 0; m < 10; ++m) {
        float acc = pe_b2[m];
#pragma unroll
        for (int k = 0; k < 5; ++k) acc = fmaf(t5[k], pe_w2[k * 10 + m], acc);
        he[m] = acc;
    }
    float base[5];
#pragma unroll
    for (int k = 0; k < 5; ++k) {
        float acc = b_nb[k];
#pragma unroll
        for (int t = 0; t < 5; ++t) acc = fmaf(t5[t], W_nb[t * 5 + k], acc);
        base[k] = acc;
    }
    float n = nodes[ii];
#pragma unroll
    for (int it = 0; it < 3; ++it) {
        float acc = b2n;
#pragma unroll
        for (int k = 0; k < 5; ++k) {
            float tt = selu_f(fmaf(n, w1r0n[k], base[k]));
            acc = fmaf(tt, w2n[k], acc);
        }
        n = acc;
    }

    int gid = valid ? graph_ids[ii] : -1;
    if (!valid) {
        n = 0.0f;
#pragma unroll
        for (int m = 0; m < 10; ++m) he[m] = 0.0f;
    }

    int gid0 = __shfl(gid, 0, 64);
    bool allsame = __all(gid == gid0) && (gid0 >= 0);
    if (allsame) {
        // sorted graph_ids -> whole wave same graph: reduce then 11 atomics
        float v = n;
#pragma unroll
        for (int off = 32; off > 0; off >>= 1) v += __shfl_down(v, off, 64);
        float vh[10];
#pragma unroll
        for (int m = 0; m < 10; ++m) {
            float w = he[m];
#pragma unroll
            for (int off = 32; off > 0; off >>= 1) w += __shfl_down(w, off, 64);
            vh[m] = w;
        }
        if ((threadIdx.x & 63) == 0) {
            atomAddF(&graph_acc[gid0 * 11 + 0], v);
#pragma unroll
            for (int m = 0; m < 10; ++m) atomAddF(&graph_acc[gid0 * 11 + 1 + m], vh[m]);
        }
    } else if (valid) {
        atomAddF(&graph_acc[gid * 11 + 0], n);
#pragma unroll
        for (int m = 0; m < 10; ++m) atomAddF(&graph_acc[gid * 11 + 1 + m], he[m]);
    }
}

__global__ void k_final(const float* __restrict__ graph_acc,
                        const float* __restrict__ pr_w1, const float* __restrict__ pr_b1,
                        const float* __restrict__ pr_w2, const float* __restrict__ pr_b2,
                        float* __restrict__ out) {
    int g = blockIdx.x * blockDim.x + threadIdx.x;
    if (g >= N_GRAPHS_C) return;
    float gv[11];
#pragma unroll
    for (int f = 0; f < 11; ++f) gv[f] = graph_acc[g * 11 + f];
    float h[10];
#pragma unroll
    for (int j = 0; j < 10; ++j) {
        float z = pr_b1[j];
#pragma unroll
        for (int f = 0; f < 11; ++f) z = fmaf(gv[f], pr_w1[f * 10 + j], z);
        h[j] = selu_f(z);
    }
    float o[10];
    float mx = -1e30f;
#pragma unroll
    for (int j = 0; j < 10; ++j) {
        float z = pr_b2[j];
#pragma unroll
        for (int m = 0; m < 10; ++m) z = fmaf(h[m], pr_w2[m * 10 + j], z);
        o[j] = z;
        mx = fmaxf(mx, z);
    }
    float sum = 0.0f;
#pragma unroll
    for (int j = 0; j < 10; ++j) { o[j] = __expf(o[j] - mx); sum += o[j]; }
    float inv = 1.0f / sum;
#pragma unroll
    for (int j = 0; j < 10; ++j) out[g * 10 + j] = o[j] * inv;
}

extern "C" void kernel_launch(void* const* d_in, const int* in_sizes, int n_in,
                              void* d_out, int out_size, void* d_ws, size_t ws_size,
                              hipStream_t stream) {
    const float* nodes     = (const float*)d_in[0];
    const float* edges     = (const float*)d_in[1];
    const int*   senders   = (const int*)d_in[2];
    const int*   receivers = (const int*)d_in[3];
    const int*   graph_ids = (const int*)d_in[4];
    const float* pn_w1 = (const float*)d_in[6];
    const float* pn_b1 = (const float*)d_in[7];
    const float* pn_w2 = (const float*)d_in[8];
    const float* pn_b2 = (const float*)d_in[9];
    const float* ue_w1 = (const float*)d_in[10];
    const float* ue_b1 = (const float*)d_in[11];
    const float* ue_w2 = (const float*)d_in[12];
    const float* ue_b2 = (const float*)d_in[13];
    const float* pe_w1 = (const float*)d_in[14];
    const float* pe_b1 = (const float*)d_in[15];
    const float* pe_w2 = (const float*)d_in[16];
    const float* pe_b2 = (const float*)d_in[17];
    const float* un_w1 = (const float*)d_in[18];
    const float* un_b1 = (const float*)d_in[19];
    const float* un_w2 = (const float*)d_in[20];
    const float* un_b2 = (const float*)d_in[21];
    const float* pr_w1 = (const float*)d_in[22];
    const float* pr_b1 = (const float*)d_in[23];
    const float* pr_w2 = (const float*)d_in[24];
    const float* pr_b2 = (const float*)d_in[25];

    float* ws = (float*)d_ws;
    float* node_acc  = ws + NODE_ACC_OFF;
    float* graph_acc = ws + GRAPH_ACC_OFF;
    float* fw        = ws + FW_OFF;
    float* outp      = (float*)d_out;

    hipLaunchKernelGGL(k_zero, dim3((ZERO_LEN + 255) / 256), dim3(256), 0, stream, ws);
    hipLaunchKernelGGL(k_fuse, dim3(1), dim3(64), 0, stream,
                       pn_w1, pn_b1, pn_w2, pn_b2, ue_w1, ue_b1, ue_w2, ue_b2,
                       pe_w1, pe_b1, pe_w2, pe_b2, un_w1, un_b1, un_w2, un_b2, fw);
    hipLaunchKernelGGL(k_edges, dim3((N_EDGES_C / 4 + 255) / 256), dim3(256), 0, stream,
                       nodes, edges, senders, receivers, fw, node_acc);
    hipLaunchKernelGGL(k_nodes, dim3((N_NODES_C + 255) / 256), dim3(256), 0, stream,
                       nodes, graph_ids, fw, node_acc, graph_acc);
    hipLaunchKernelGGL(k_final, dim3((N_GRAPHS_C + 255) / 256), dim3(256), 0, stream,
                       graph_acc, pr_w1, pr_b1, pr_w2, pr_b2, outp);
}